// Round 3
// baseline (165.210 us; speedup 1.0000x reference)
//
#include <hip/hip_runtime.h>

#define N_NODES   20000
#define N_ANCHORS 64
#define D         128
#define N_EDGES   (N_NODES * N_ANCHORS)

// ---- bf16 helpers (round-to-nearest-even pack, shift unpack) ----
static __device__ __forceinline__ unsigned short f32_to_bf16(float x) {
    unsigned int u = __float_as_uint(x);
    u += 0x7FFFu + ((u >> 16) & 1u);   // RNE
    return (unsigned short)(u >> 16);
}
static __device__ __forceinline__ float bf_lo(unsigned int w) {
    return __uint_as_float(w << 16);
}
static __device__ __forceinline__ float bf_hi(unsigned int w) {
    return __uint_as_float(w & 0xFFFF0000u);
}

// ---------------- Kernel 1: u/v projections, f32 compute, bf16 output
__global__ __launch_bounds__(256) void proj_kernel(
    const float* __restrict__ feature,
    const float* __restrict__ Wu, const float* __restrict__ bu,
    const float* __restrict__ Wv, const float* __restrict__ bv,
    unsigned short* __restrict__ u_bf, unsigned short* __restrict__ v_bf)
{
    __shared__ float f[16 * D];   // 8 KiB feature tile
    const int tid = threadIdx.x;
    const int n0  = blockIdx.x * 16;

    {
        const float4* g4 = (const float4*)(feature + (size_t)n0 * D);
        float4* f4 = (float4*)f;
        f4[tid]       = g4[tid];
        f4[tid + 256] = g4[tid + 256];
    }
    __syncthreads();

    const int j = tid & 127;
    const int g = tid >> 7;

    float accu[8], accv[8];
    const float buj = bu[j], bvj = bv[j];
    #pragma unroll
    for (int r = 0; r < 8; ++r) { accu[r] = buj; accv[r] = bvj; }

    for (int k = 0; k < D; k += 4) {
        const float wu0 = Wu[(k + 0) * D + j];
        const float wu1 = Wu[(k + 1) * D + j];
        const float wu2 = Wu[(k + 2) * D + j];
        const float wu3 = Wu[(k + 3) * D + j];
        const float wv0 = Wv[(k + 0) * D + j];
        const float wv1 = Wv[(k + 1) * D + j];
        const float wv2 = Wv[(k + 2) * D + j];
        const float wv3 = Wv[(k + 3) * D + j];
        #pragma unroll
        for (int r = 0; r < 8; ++r) {
            const float4 fr = *(const float4*)&f[(g * 8 + r) * D + k];
            accu[r] = fmaf(fr.x, wu0, accu[r]);
            accu[r] = fmaf(fr.y, wu1, accu[r]);
            accu[r] = fmaf(fr.z, wu2, accu[r]);
            accu[r] = fmaf(fr.w, wu3, accu[r]);
            accv[r] = fmaf(fr.x, wv0, accv[r]);
            accv[r] = fmaf(fr.y, wv1, accv[r]);
            accv[r] = fmaf(fr.z, wv2, accv[r]);
            accv[r] = fmaf(fr.w, wv3, accv[r]);
        }
    }

    #pragma unroll
    for (int r = 0; r < 8; ++r) {
        const int n = n0 + g * 8 + r;
        u_bf[(size_t)n * D + j] = f32_to_bf16(accu[r]);
        v_bf[(size_t)n * D + j] = f32_to_bf16(accv[r]);
    }
}

// ---------------- Kernel 2: edge gather (bf16 rows), deep-unrolled for MLP.
// 256 threads = 4 waves; one wave per node. Anchors in 2 halves of 32;
// per half: issue all 16 uint4 gathers (8 anchors-steps x {u,v}) BEFORE
// consuming -> ~256 B in flight per lane.
__global__ __launch_bounds__(256) void edge_kernel(
    const unsigned short* __restrict__ u_bf, const unsigned short* __restrict__ v_bf,
    const float* __restrict__ sp_dist, const int* __restrict__ src,
    const int* __restrict__ dst, const int* __restrict__ anchor_eid,
    const float* __restrict__ Wpos, const float* __restrict__ bpos,
    float* __restrict__ out_pos, float* __restrict__ out_struct)
{
    const int wave = threadIdx.x >> 6;       // 0..3
    const int lane = threadIdx.x & 63;
    const int n    = blockIdx.x * 4 + wave;  // 5000*4 = 20000 exact

    const int sub = lane & 15;               // dims [sub*8, sub*8+8)
    const int grp = lane >> 4;               // anchor sub-slot 0..3

    const int   e   = n * N_ANCHORS + lane;
    const int   eid = anchor_eid[e];
    const int   s   = src[eid];
    const int   d   = dst[eid];
    const float sp  = sp_dist[eid];

    const float4 wpA = ((const float4*)Wpos)[sub * 2];
    const float4 wpB = ((const float4*)Wpos)[sub * 2 + 1];

    float acc[8];
    #pragma unroll
    for (int k = 0; k < 8; ++k) acc[k] = 0.f;

    __shared__ float posbuf[4][N_ANCHORS];

    #pragma unroll
    for (int half = 0; half < 2; ++half) {
        const int abase = half * 32;
        uint4 ub[8], vb[8];

        // -------- issue phase: 16 independent gathers
        #pragma unroll
        for (int t = 0; t < 8; ++t) {
            const int a  = abase + t * 4 + grp;
            const int sa = __shfl(s, a);
            const int da = __shfl(d, a);
            ub[t] = *(const uint4*)(u_bf + (size_t)sa * D + sub * 8);
            vb[t] = *(const uint4*)(v_bf + (size_t)da * D + sub * 8);
        }

        // -------- consume phase
        #pragma unroll
        for (int t = 0; t < 8; ++t) {
            const int a = abase + t * 4 + grp;
            const float spa = __shfl(sp, a);
            const uint4 uu = ub[t];
            const uint4 vv = vb[t];

            float m[8];
            m[0] = fmaf(bf_lo(uu.x), spa, bf_lo(vv.x));
            m[1] = fmaf(bf_hi(uu.x), spa, bf_hi(vv.x));
            m[2] = fmaf(bf_lo(uu.y), spa, bf_lo(vv.y));
            m[3] = fmaf(bf_hi(uu.y), spa, bf_hi(vv.y));
            m[4] = fmaf(bf_lo(uu.z), spa, bf_lo(vv.z));
            m[5] = fmaf(bf_hi(uu.z), spa, bf_hi(vv.z));
            m[6] = fmaf(bf_lo(uu.w), spa, bf_lo(vv.w));
            m[7] = fmaf(bf_hi(uu.w), spa, bf_hi(vv.w));
            #pragma unroll
            for (int k = 0; k < 8; ++k) m[k] = fmaxf(m[k], 0.f);
            #pragma unroll
            for (int k = 0; k < 8; ++k) acc[k] += m[k];

            float p = m[0] * wpA.x + m[1] * wpA.y + m[2] * wpA.z + m[3] * wpA.w
                    + m[4] * wpB.x + m[5] * wpB.y + m[6] * wpB.z + m[7] * wpB.w;
            p += __shfl_xor(p, 8);
            p += __shfl_xor(p, 4);
            p += __shfl_xor(p, 2);
            p += __shfl_xor(p, 1);
            if (sub == 0) posbuf[wave][a] = p;
        }
    }

    #pragma unroll
    for (int k = 0; k < 8; ++k) {
        acc[k] += __shfl_xor(acc[k], 16);
        acc[k] += __shfl_xor(acc[k], 32);
    }

    __syncthreads();

    const float bp = bpos[0];
    out_pos[(size_t)n * N_ANCHORS + lane] = posbuf[wave][lane] + bp;

    if (grp == 0) {
        const float inv = 1.0f / (float)N_ANCHORS;
        float4 o0, o1;
        o0.x = acc[0] * inv; o0.y = acc[1] * inv; o0.z = acc[2] * inv; o0.w = acc[3] * inv;
        o1.x = acc[4] * inv; o1.y = acc[5] * inv; o1.z = acc[6] * inv; o1.w = acc[7] * inv;
        float4* os = (float4*)(out_struct + (size_t)n * D + sub * 8);
        os[0] = o0;
        os[1] = o1;
    }
}

extern "C" void kernel_launch(void* const* d_in, const int* in_sizes, int n_in,
                              void* d_out, int out_size, void* d_ws, size_t ws_size,
                              hipStream_t stream) {
    const float* feature    = (const float*)d_in[0];
    const float* sp_dist    = (const float*)d_in[1];
    const float* Wu         = (const float*)d_in[2];
    const float* bu         = (const float*)d_in[3];
    const float* Wv         = (const float*)d_in[4];
    const float* bv         = (const float*)d_in[5];
    const float* Wpos       = (const float*)d_in[6];
    const float* bpos       = (const float*)d_in[7];
    const int*   src        = (const int*)d_in[8];
    const int*   dst        = (const int*)d_in[9];
    const int*   anchor_eid = (const int*)d_in[10];

    unsigned short* u_bf = (unsigned short*)d_ws;
    unsigned short* v_bf = u_bf + (size_t)N_NODES * D;

    float* out_pos    = (float*)d_out;
    float* out_struct = out_pos + (size_t)N_EDGES;

    proj_kernel<<<N_NODES / 16, 256, 0, stream>>>(feature, Wu, bu, Wv, bv,
                                                  u_bf, v_bf);
    edge_kernel<<<N_NODES / 4, 256, 0, stream>>>(u_bf, v_bf, sp_dist, src,
                                                 dst, anchor_eid, Wpos, bpos,
                                                 out_pos, out_struct);
}

// Round 5
// 164.518 us; speedup vs baseline: 1.0042x; 1.0042x over previous
//
#include <hip/hip_runtime.h>

#define N_NODES   20000
#define N_ANCHORS 64
#define D         128
#define N_EDGES   (N_NODES * N_ANCHORS)
#define NCHUNK    4
#define CDIM      32          // dims per chunk

typedef float  f32x4 __attribute__((ext_vector_type(4)));

// ---- bf16 helpers (round-to-nearest-even pack, shift unpack) ----
static __device__ __forceinline__ unsigned short f32_to_bf16(float x) {
    unsigned int u = __float_as_uint(x);
    u += 0x7FFFu + ((u >> 16) & 1u);   // RNE
    return (unsigned short)(u >> 16);
}
static __device__ __forceinline__ float bf_lo(unsigned int w) {
    return __uint_as_float(w << 16);
}
static __device__ __forceinline__ float bf_hi(unsigned int w) {
    return __uint_as_float(w & 0xFFFF0000u);
}

// ---------------- Kernel 1: u/v projections, f32 compute, bf16 CHUNK-MAJOR out
// u_c[chunk][node][32], v_c likewise. 16 nodes/block, j=col, g=node-half.
__global__ __launch_bounds__(256) void proj_kernel(
    const float* __restrict__ feature,
    const float* __restrict__ Wu, const float* __restrict__ bu,
    const float* __restrict__ Wv, const float* __restrict__ bv,
    unsigned short* __restrict__ u_c, unsigned short* __restrict__ v_c)
{
    __shared__ float f[16 * D];   // 8 KiB feature tile
    const int tid = threadIdx.x;
    const int n0  = blockIdx.x * 16;

    {
        const float4* g4 = (const float4*)(feature + (size_t)n0 * D);
        float4* f4 = (float4*)f;
        f4[tid]       = g4[tid];
        f4[tid + 256] = g4[tid + 256];
    }
    __syncthreads();

    const int j = tid & 127;
    const int g = tid >> 7;
    const int cj   = j >> 5;       // chunk of this col
    const int dimc = j & 31;       // dim within chunk

    float accu[8], accv[8];
    const float buj = bu[j], bvj = bv[j];
    #pragma unroll
    for (int r = 0; r < 8; ++r) { accu[r] = buj; accv[r] = bvj; }

    for (int k = 0; k < D; k += 4) {
        const float wu0 = Wu[(k + 0) * D + j];
        const float wu1 = Wu[(k + 1) * D + j];
        const float wu2 = Wu[(k + 2) * D + j];
        const float wu3 = Wu[(k + 3) * D + j];
        const float wv0 = Wv[(k + 0) * D + j];
        const float wv1 = Wv[(k + 1) * D + j];
        const float wv2 = Wv[(k + 2) * D + j];
        const float wv3 = Wv[(k + 3) * D + j];
        #pragma unroll
        for (int r = 0; r < 8; ++r) {
            const float4 fr = *(const float4*)&f[(g * 8 + r) * D + k];
            accu[r] = fmaf(fr.x, wu0, accu[r]);
            accu[r] = fmaf(fr.y, wu1, accu[r]);
            accu[r] = fmaf(fr.z, wu2, accu[r]);
            accu[r] = fmaf(fr.w, wu3, accu[r]);
            accv[r] = fmaf(fr.x, wv0, accv[r]);
            accv[r] = fmaf(fr.y, wv1, accv[r]);
            accv[r] = fmaf(fr.z, wv2, accv[r]);
            accv[r] = fmaf(fr.w, wv3, accv[r]);
        }
    }

    #pragma unroll
    for (int r = 0; r < 8; ++r) {
        const int n = n0 + g * 8 + r;
        const size_t idx = ((size_t)cj * N_NODES + n) * CDIM + dimc;
        u_c[idx] = f32_to_bf16(accu[r]);
        v_c[idx] = f32_to_bf16(accv[r]);
    }
}

// ---------------- Kernel 2: pack edge meta once: {s | d<<15, sp} as u64
__global__ __launch_bounds__(256) void meta_kernel(
    const int* __restrict__ src, const int* __restrict__ dst,
    const float* __restrict__ sp_dist, const int* __restrict__ anchor_eid,
    unsigned long long* __restrict__ meta)
{
    const int e = blockIdx.x * 256 + threadIdx.x;
    const int eid = anchor_eid[e];
    const unsigned int s = (unsigned int)src[eid];
    const unsigned int d = (unsigned int)dst[eid];
    const float sp = sp_dist[eid];
    const unsigned long long m =
        (unsigned long long)(s | (d << 15)) |
        ((unsigned long long)__float_as_uint(sp) << 32);
    meta[e] = m;
}

// ---------------- Kernel 3: one chunk pass. Table chunk (2.56 MB) is
// L2-resident; meta/outputs use nontemporal accesses to avoid evicting it.
// 4 waves/block = 4 nodes. lane: sub=lane&3 (8 dims), grp=lane>>2 (anchor slot).
__global__ __launch_bounds__(256) void chunk_kernel(
    const unsigned short* __restrict__ u_c, const unsigned short* __restrict__ v_c,
    const unsigned long long* __restrict__ meta,
    const float* __restrict__ Wpos, const float* __restrict__ bpos,
    float* __restrict__ out_pos, float* __restrict__ out_struct,
    int chunk)
{
    const int wave = threadIdx.x >> 6;
    const int lane = threadIdx.x & 63;
    const int n    = blockIdx.x * 4 + wave;   // 5000*4 = 20000 exact

    const int sub = lane & 3;                 // dims [sub*8, sub*8+8) of chunk
    const int grp = lane >> 2;                // anchor sub-slot 0..15

    // per-lane meta for anchor `lane`
    const unsigned long long mm =
        __builtin_nontemporal_load(&meta[(size_t)n * N_ANCHORS + lane]);
    const int   s  = (int)(mm & 0x7FFFu);
    const int   d  = (int)((mm >> 15) & 0x7FFFu);
    const float sp = __uint_as_float((unsigned int)(mm >> 32));

    // Wpos fragment: dims chunk*32 + sub*8 .. +8
    const float4 wpA = ((const float4*)Wpos)[chunk * 8 + sub * 2];
    const float4 wpB = ((const float4*)Wpos)[chunk * 8 + sub * 2 + 1];

    const unsigned short* ub = u_c + (size_t)chunk * N_NODES * CDIM;
    const unsigned short* vb = v_c + (size_t)chunk * N_NODES * CDIM;

    float acc[8];
    #pragma unroll
    for (int k = 0; k < 8; ++k) acc[k] = 0.f;

    __shared__ float posbuf[4][N_ANCHORS];

    #pragma unroll
    for (int it = 0; it < 4; ++it) {
        const int a = it * 16 + grp;
        const int   sa  = __shfl(s,  a);
        const int   da  = __shfl(d,  a);
        const float spa = __shfl(sp, a);

        const uint4 uu = *(const uint4*)(ub + (size_t)sa * CDIM + sub * 8);
        const uint4 vv = *(const uint4*)(vb + (size_t)da * CDIM + sub * 8);

        float m[8];
        m[0] = fmaf(bf_lo(uu.x), spa, bf_lo(vv.x));
        m[1] = fmaf(bf_hi(uu.x), spa, bf_hi(vv.x));
        m[2] = fmaf(bf_lo(uu.y), spa, bf_lo(vv.y));
        m[3] = fmaf(bf_hi(uu.y), spa, bf_hi(vv.y));
        m[4] = fmaf(bf_lo(uu.z), spa, bf_lo(vv.z));
        m[5] = fmaf(bf_hi(uu.z), spa, bf_hi(vv.z));
        m[6] = fmaf(bf_lo(uu.w), spa, bf_lo(vv.w));
        m[7] = fmaf(bf_hi(uu.w), spa, bf_hi(vv.w));
        #pragma unroll
        for (int k = 0; k < 8; ++k) m[k] = fmaxf(m[k], 0.f);
        #pragma unroll
        for (int k = 0; k < 8; ++k) acc[k] += m[k];

        float p = m[0] * wpA.x + m[1] * wpA.y + m[2] * wpA.z + m[3] * wpA.w
                + m[4] * wpB.x + m[5] * wpB.y + m[6] * wpB.z + m[7] * wpB.w;
        p += __shfl_xor(p, 2);
        p += __shfl_xor(p, 1);
        if (sub == 0) posbuf[wave][a] = p;
    }

    // reduce struct partials over the 16 anchor groups (lane bits 2..5)
    #pragma unroll
    for (int k = 0; k < 8; ++k) {
        acc[k] += __shfl_xor(acc[k], 4);
        acc[k] += __shfl_xor(acc[k], 8);
        acc[k] += __shfl_xor(acc[k], 16);
        acc[k] += __shfl_xor(acc[k], 32);
    }

    __syncthreads();

    // position: accumulate across chunk passes directly in out_pos
    {
        const size_t oi = (size_t)n * N_ANCHORS + lane;
        const float pv = posbuf[wave][lane];
        if (chunk == 0) {
            __builtin_nontemporal_store(pv, &out_pos[oi]);
        } else if (chunk < NCHUNK - 1) {
            const float prev = __builtin_nontemporal_load(&out_pos[oi]);
            __builtin_nontemporal_store(prev + pv, &out_pos[oi]);
        } else {
            const float prev = __builtin_nontemporal_load(&out_pos[oi]);
            __builtin_nontemporal_store(prev + pv + bpos[0], &out_pos[oi]);
        }
    }

    // structure: this chunk owns dims [chunk*32, chunk*32+32) — disjoint
    if (grp == 0) {
        const float inv = 1.0f / (float)N_ANCHORS;
        f32x4 o0, o1;
        o0.x = acc[0] * inv; o0.y = acc[1] * inv; o0.z = acc[2] * inv; o0.w = acc[3] * inv;
        o1.x = acc[4] * inv; o1.y = acc[5] * inv; o1.z = acc[6] * inv; o1.w = acc[7] * inv;
        float* os = out_struct + (size_t)n * D + chunk * CDIM + sub * 8;
        __builtin_nontemporal_store(o0, (f32x4*)os);
        __builtin_nontemporal_store(o1, (f32x4*)(os + 4));
    }
}

extern "C" void kernel_launch(void* const* d_in, const int* in_sizes, int n_in,
                              void* d_out, int out_size, void* d_ws, size_t ws_size,
                              hipStream_t stream) {
    const float* feature    = (const float*)d_in[0];
    const float* sp_dist    = (const float*)d_in[1];
    const float* Wu         = (const float*)d_in[2];
    const float* bu         = (const float*)d_in[3];
    const float* Wv         = (const float*)d_in[4];
    const float* bv         = (const float*)d_in[5];
    const float* Wpos       = (const float*)d_in[6];
    const float* bpos       = (const float*)d_in[7];
    const int*   src        = (const int*)d_in[8];
    const int*   dst        = (const int*)d_in[9];
    const int*   anchor_eid = (const int*)d_in[10];

    // ws layout: u_c (5.12 MB) | v_c (5.12 MB) | meta (10.24 MB) = 20.48 MB
    unsigned short* u_c = (unsigned short*)d_ws;
    unsigned short* v_c = u_c + (size_t)NCHUNK * N_NODES * CDIM;
    unsigned long long* meta =
        (unsigned long long*)(v_c + (size_t)NCHUNK * N_NODES * CDIM);

    float* out_pos    = (float*)d_out;
    float* out_struct = out_pos + (size_t)N_EDGES;

    proj_kernel<<<N_NODES / 16, 256, 0, stream>>>(feature, Wu, bu, Wv, bv,
                                                  u_c, v_c);
    meta_kernel<<<N_EDGES / 256, 256, 0, stream>>>(src, dst, sp_dist,
                                                   anchor_eid, meta);
    for (int c = 0; c < NCHUNK; ++c) {
        chunk_kernel<<<N_NODES / 4, 256, 0, stream>>>(u_c, v_c, meta, Wpos,
                                                      bpos, out_pos, out_struct,
                                                      c);
    }
}

// Round 6
// 142.985 us; speedup vs baseline: 1.1554x; 1.1506x over previous
//
#include <hip/hip_runtime.h>

#define N_NODES   20000
#define N_ANCHORS 64
#define D         128
#define N_EDGES   (N_NODES * N_ANCHORS)
#define NCHUNK    4
#define CDIM      32          // dims per chunk

typedef float  f32x4 __attribute__((ext_vector_type(4)));

// ---- bf16 helpers (round-to-nearest-even pack, shift unpack) ----
static __device__ __forceinline__ unsigned short f32_to_bf16(float x) {
    unsigned int u = __float_as_uint(x);
    u += 0x7FFFu + ((u >> 16) & 1u);   // RNE
    return (unsigned short)(u >> 16);
}
static __device__ __forceinline__ float bf_lo(unsigned int w) {
    return __uint_as_float(w << 16);
}
static __device__ __forceinline__ float bf_hi(unsigned int w) {
    return __uint_as_float(w & 0xFFFF0000u);
}

// ---------------- Kernel 0: pack per-ORIGINAL-edge records {s|d<<15, sp}
// pure linear streams; epack will be gathered by meta_kernel next.
__global__ __launch_bounds__(256) void pack_kernel(
    const int* __restrict__ src, const int* __restrict__ dst,
    const float* __restrict__ sp_dist,
    unsigned long long* __restrict__ epack)
{
    const int e = blockIdx.x * 256 + threadIdx.x;
    const unsigned int s = (unsigned int)__builtin_nontemporal_load(&src[e]);
    const unsigned int d = (unsigned int)__builtin_nontemporal_load(&dst[e]);
    const float       sp = __builtin_nontemporal_load(&sp_dist[e]);
    epack[e] = (unsigned long long)(s | (d << 15)) |
               ((unsigned long long)__float_as_uint(sp) << 32);
}

// ---------------- Kernel 1: meta[e] = epack[anchor_eid[e]] — ONE 8B gather
__global__ __launch_bounds__(256) void meta_kernel(
    const unsigned long long* __restrict__ epack,
    const int* __restrict__ anchor_eid,
    unsigned long long* __restrict__ meta)
{
    const int e = blockIdx.x * 256 + threadIdx.x;
    const int eid = __builtin_nontemporal_load(&anchor_eid[e]);
    const unsigned long long m = epack[eid];
    __builtin_nontemporal_store(m, &meta[e]);
}

// ---------------- Kernel 2: u/v projections, f32 compute, bf16 CHUNK-MAJOR out
// u_c[chunk][node][32], v_c likewise. 16 nodes/block, j=col, g=node-half.
__global__ __launch_bounds__(256) void proj_kernel(
    const float* __restrict__ feature,
    const float* __restrict__ Wu, const float* __restrict__ bu,
    const float* __restrict__ Wv, const float* __restrict__ bv,
    unsigned short* __restrict__ u_c, unsigned short* __restrict__ v_c)
{
    __shared__ float f[16 * D];   // 8 KiB feature tile
    const int tid = threadIdx.x;
    const int n0  = blockIdx.x * 16;

    {
        const float4* g4 = (const float4*)(feature + (size_t)n0 * D);
        float4* f4 = (float4*)f;
        f4[tid]       = g4[tid];
        f4[tid + 256] = g4[tid + 256];
    }
    __syncthreads();

    const int j = tid & 127;
    const int g = tid >> 7;
    const int cj   = j >> 5;       // chunk of this col
    const int dimc = j & 31;       // dim within chunk

    float accu[8], accv[8];
    const float buj = bu[j], bvj = bv[j];
    #pragma unroll
    for (int r = 0; r < 8; ++r) { accu[r] = buj; accv[r] = bvj; }

    for (int k = 0; k < D; k += 4) {
        const float wu0 = Wu[(k + 0) * D + j];
        const float wu1 = Wu[(k + 1) * D + j];
        const float wu2 = Wu[(k + 2) * D + j];
        const float wu3 = Wu[(k + 3) * D + j];
        const float wv0 = Wv[(k + 0) * D + j];
        const float wv1 = Wv[(k + 1) * D + j];
        const float wv2 = Wv[(k + 2) * D + j];
        const float wv3 = Wv[(k + 3) * D + j];
        #pragma unroll
        for (int r = 0; r < 8; ++r) {
            const float4 fr = *(const float4*)&f[(g * 8 + r) * D + k];
            accu[r] = fmaf(fr.x, wu0, accu[r]);
            accu[r] = fmaf(fr.y, wu1, accu[r]);
            accu[r] = fmaf(fr.z, wu2, accu[r]);
            accu[r] = fmaf(fr.w, wu3, accu[r]);
            accv[r] = fmaf(fr.x, wv0, accv[r]);
            accv[r] = fmaf(fr.y, wv1, accv[r]);
            accv[r] = fmaf(fr.z, wv2, accv[r]);
            accv[r] = fmaf(fr.w, wv3, accv[r]);
        }
    }

    #pragma unroll
    for (int r = 0; r < 8; ++r) {
        const int n = n0 + g * 8 + r;
        const size_t idx = ((size_t)cj * N_NODES + n) * CDIM + dimc;
        u_c[idx] = f32_to_bf16(accu[r]);
        v_c[idx] = f32_to_bf16(accv[r]);
    }
}

// ---------------- Kernel 3: one chunk pass. Table chunk (2.56 MB u+v) is
// L2-resident; meta/outputs use nontemporal accesses to avoid evicting it.
// 4 waves/block = 4 nodes. lane: sub=lane&3 (8 dims), grp=lane>>2 (anchor slot).
__global__ __launch_bounds__(256) void chunk_kernel(
    const unsigned short* __restrict__ u_c, const unsigned short* __restrict__ v_c,
    const unsigned long long* __restrict__ meta,
    const float* __restrict__ Wpos, const float* __restrict__ bpos,
    float* __restrict__ out_pos, float* __restrict__ out_struct,
    int chunk)
{
    const int wave = threadIdx.x >> 6;
    const int lane = threadIdx.x & 63;
    const int n    = blockIdx.x * 4 + wave;   // 5000*4 = 20000 exact

    const int sub = lane & 3;                 // dims [sub*8, sub*8+8) of chunk
    const int grp = lane >> 2;                // anchor sub-slot 0..15

    // per-lane meta for anchor `lane`
    const unsigned long long mm =
        __builtin_nontemporal_load(&meta[(size_t)n * N_ANCHORS + lane]);
    const int   s  = (int)(mm & 0x7FFFu);
    const int   d  = (int)((mm >> 15) & 0x7FFFu);
    const float sp = __uint_as_float((unsigned int)(mm >> 32));

    // Wpos fragment: dims chunk*32 + sub*8 .. +8
    const float4 wpA = ((const float4*)Wpos)[chunk * 8 + sub * 2];
    const float4 wpB = ((const float4*)Wpos)[chunk * 8 + sub * 2 + 1];

    const unsigned short* ub = u_c + (size_t)chunk * N_NODES * CDIM;
    const unsigned short* vb = v_c + (size_t)chunk * N_NODES * CDIM;

    float acc[8];
    #pragma unroll
    for (int k = 0; k < 8; ++k) acc[k] = 0.f;

    __shared__ float posbuf[4][N_ANCHORS];

    #pragma unroll
    for (int it = 0; it < 4; ++it) {
        const int a = it * 16 + grp;
        const int   sa  = __shfl(s,  a);
        const int   da  = __shfl(d,  a);
        const float spa = __shfl(sp, a);

        const uint4 uu = *(const uint4*)(ub + (size_t)sa * CDIM + sub * 8);
        const uint4 vv = *(const uint4*)(vb + (size_t)da * CDIM + sub * 8);

        float m[8];
        m[0] = fmaf(bf_lo(uu.x), spa, bf_lo(vv.x));
        m[1] = fmaf(bf_hi(uu.x), spa, bf_hi(vv.x));
        m[2] = fmaf(bf_lo(uu.y), spa, bf_lo(vv.y));
        m[3] = fmaf(bf_hi(uu.y), spa, bf_hi(vv.y));
        m[4] = fmaf(bf_lo(uu.z), spa, bf_lo(vv.z));
        m[5] = fmaf(bf_hi(uu.z), spa, bf_hi(vv.z));
        m[6] = fmaf(bf_lo(uu.w), spa, bf_lo(vv.w));
        m[7] = fmaf(bf_hi(uu.w), spa, bf_hi(vv.w));
        #pragma unroll
        for (int k = 0; k < 8; ++k) m[k] = fmaxf(m[k], 0.f);
        #pragma unroll
        for (int k = 0; k < 8; ++k) acc[k] += m[k];

        float p = m[0] * wpA.x + m[1] * wpA.y + m[2] * wpA.z + m[3] * wpA.w
                + m[4] * wpB.x + m[5] * wpB.y + m[6] * wpB.z + m[7] * wpB.w;
        p += __shfl_xor(p, 2);
        p += __shfl_xor(p, 1);
        if (sub == 0) posbuf[wave][a] = p;
    }

    // reduce struct partials over the 16 anchor groups (lane bits 2..5)
    #pragma unroll
    for (int k = 0; k < 8; ++k) {
        acc[k] += __shfl_xor(acc[k], 4);
        acc[k] += __shfl_xor(acc[k], 8);
        acc[k] += __shfl_xor(acc[k], 16);
        acc[k] += __shfl_xor(acc[k], 32);
    }

    __syncthreads();

    // position: accumulate across chunk passes directly in out_pos
    {
        const size_t oi = (size_t)n * N_ANCHORS + lane;
        const float pv = posbuf[wave][lane];
        if (chunk == 0) {
            __builtin_nontemporal_store(pv, &out_pos[oi]);
        } else if (chunk < NCHUNK - 1) {
            const float prev = __builtin_nontemporal_load(&out_pos[oi]);
            __builtin_nontemporal_store(prev + pv, &out_pos[oi]);
        } else {
            const float prev = __builtin_nontemporal_load(&out_pos[oi]);
            __builtin_nontemporal_store(prev + pv + bpos[0], &out_pos[oi]);
        }
    }

    // structure: this chunk owns dims [chunk*32, chunk*32+32) — disjoint
    if (grp == 0) {
        const float inv = 1.0f / (float)N_ANCHORS;
        f32x4 o0, o1;
        o0.x = acc[0] * inv; o0.y = acc[1] * inv; o0.z = acc[2] * inv; o0.w = acc[3] * inv;
        o1.x = acc[4] * inv; o1.y = acc[5] * inv; o1.z = acc[6] * inv; o1.w = acc[7] * inv;
        float* os = out_struct + (size_t)n * D + chunk * CDIM + sub * 8;
        __builtin_nontemporal_store(o0, (f32x4*)os);
        __builtin_nontemporal_store(o1, (f32x4*)(os + 4));
    }
}

extern "C" void kernel_launch(void* const* d_in, const int* in_sizes, int n_in,
                              void* d_out, int out_size, void* d_ws, size_t ws_size,
                              hipStream_t stream) {
    const float* feature    = (const float*)d_in[0];
    const float* sp_dist    = (const float*)d_in[1];
    const float* Wu         = (const float*)d_in[2];
    const float* bu         = (const float*)d_in[3];
    const float* Wv         = (const float*)d_in[4];
    const float* bv         = (const float*)d_in[5];
    const float* Wpos       = (const float*)d_in[6];
    const float* bpos       = (const float*)d_in[7];
    const int*   src        = (const int*)d_in[8];
    const int*   dst        = (const int*)d_in[9];
    const int*   anchor_eid = (const int*)d_in[10];

    // ws layout (20.48 MB total, same as before):
    //   region X [0, 10.24 MB): epack first, then overwritten by u_c|v_c
    //   region Y [10.24, 20.48 MB): meta
    unsigned short* u_c = (unsigned short*)d_ws;
    unsigned short* v_c = u_c + (size_t)NCHUNK * N_NODES * CDIM;
    unsigned long long* epack = (unsigned long long*)d_ws;   // aliases u_c/v_c
    unsigned long long* meta =
        (unsigned long long*)((char*)d_ws + (size_t)2 * NCHUNK * N_NODES * CDIM * 2);

    float* out_pos    = (float*)d_out;
    float* out_struct = out_pos + (size_t)N_EDGES;

    // order matters: epack lives in region X until meta_kernel finishes;
    // proj_kernel then overwrites region X with u_c/v_c.
    pack_kernel<<<N_EDGES / 256, 256, 0, stream>>>(src, dst, sp_dist, epack);
    meta_kernel<<<N_EDGES / 256, 256, 0, stream>>>(epack, anchor_eid, meta);
    proj_kernel<<<N_NODES / 16, 256, 0, stream>>>(feature, Wu, bu, Wv, bv,
                                                  u_c, v_c);
    for (int c = 0; c < NCHUNK; ++c) {
        chunk_kernel<<<N_NODES / 4, 256, 0, stream>>>(u_c, v_c, meta, Wpos,
                                                      bpos, out_pos, out_struct,
                                                      c);
    }
}